// Round 7
// baseline (227.785 us; speedup 1.0000x reference)
//
#include <hip/hip_runtime.h>
#include <hip/hip_bf16.h>
#include <stdint.h>

typedef unsigned short u16;
typedef __attribute__((ext_vector_type(8))) short short8;
typedef __attribute__((ext_vector_type(16))) float f32x16;

#define BATCH 4096
#define DIN   1024
#define NH    1024
#define KTOT  2048
#define BM    128
#define BN    32
#define BK    64

__device__ __forceinline__ void gload_lds16(const void* gp, void* lp) {
    __builtin_amdgcn_global_load_lds(
        (const __attribute__((address_space(1))) uint32_t*)gp,
        (__attribute__((address_space(3))) uint32_t*)lp, 16, 0, 0);
}

__device__ __forceinline__ u16 f2bf(float f) {   // round-to-nearest-even
    uint32_t t; __builtin_memcpy(&t, &f, 4);
    uint32_t r = (t + 0x7FFFu + ((t >> 16) & 1u)) >> 16;
    return (u16)r;
}
__device__ __forceinline__ float hsig(float z) {
    return fminf(fmaxf(fmaf(z, 0.2f, 0.5f), 0.0f), 1.0f);
}
__device__ __forceinline__ float fast_tanh(float x) {
    x = fminf(fmaxf(x, -12.0f), 12.0f);
    float e = __expf(2.0f * x);
    return (e - 1.0f) / (e + 1.0f);
}

// ---------------------------------------------------------------------------
// Kernel 0: cast+concat activations: Abuf[m][k] (bf16, KTOT stride)
// ---------------------------------------------------------------------------
__global__ __launch_bounds__(256) void acast_kernel(
    const float* __restrict__ x, const float* __restrict__ h0,
    u16* __restrict__ Abuf)
{
    const int c  = blockIdx.x * 256 + threadIdx.x;   // chunk id, 8 elems each
    const int m  = c >> 8;                           // KTOT/8 = 256 chunks/row
    const int kc = (c & 255) * 8;
    const float* src = (kc < DIN) ? (x + (size_t)m * DIN + kc)
                                  : (h0 + (size_t)m * DIN + (kc - DIN));
    float4 v0 = *(const float4*)(src);
    float4 v1 = *(const float4*)(src + 4);
    union { u16 v[8]; uint4 q; } pk;
    pk.v[0] = f2bf(v0.x); pk.v[1] = f2bf(v0.y);
    pk.v[2] = f2bf(v0.z); pk.v[3] = f2bf(v0.w);
    pk.v[4] = f2bf(v1.x); pk.v[5] = f2bf(v1.y);
    pk.v[6] = f2bf(v1.z); pk.v[7] = f2bf(v1.w);
    *(uint4*)(Abuf + (size_t)m * KTOT + kc) = pk.q;
}

// ---------------------------------------------------------------------------
// Kernel 1: cast + transpose + concat weights into Bt[(g*NH + n)][KTOT] bf16
// ---------------------------------------------------------------------------
__global__ __launch_bounds__(256) void wtrans_kernel(
    const float* __restrict__ Wf, const float* __restrict__ Wi,
    const float* __restrict__ Wo, const float* __restrict__ Wc,
    const float* __restrict__ Uf, const float* __restrict__ Ui,
    const float* __restrict__ Uo, const float* __restrict__ Uc,
    u16* __restrict__ Bt)
{
    __shared__ u16 tile[64][65];
    const int mz = blockIdx.z;     // 0..7: Wf,Wi,Wo,Wc,Uf,Ui,Uo,Uc
    const float* srcs[8] = {Wf, Wi, Wo, Wc, Uf, Ui, Uo, Uc};
    const float* src = srcs[mz];
    const int g    = mz & 3;
    const int koff = (mz >> 2) << 10;
    const int k0 = blockIdx.x * 64;
    const int n0 = blockIdx.y * 64;
    const int tid = threadIdx.x;

#pragma unroll
    for (int i = 0; i < 4; i++) {
        int idx = i * 256 + tid;
        int kk = idx >> 4, c = idx & 15;
        float4 v = *(const float4*)(src + (size_t)(k0 + kk) * NH + n0 + c * 4);
        u16* dst = &tile[kk][c * 4];
        dst[0] = f2bf(v.x); dst[1] = f2bf(v.y);
        dst[2] = f2bf(v.z); dst[3] = f2bf(v.w);
    }
    __syncthreads();
#pragma unroll
    for (int i = 0; i < 2; i++) {
        int idx = i * 256 + tid;
        int nn = idx >> 3, c = idx & 7;
        union { u16 v[8]; uint4 q; } pk;
#pragma unroll
        for (int j = 0; j < 8; j++) pk.v[j] = tile[c * 8 + j][nn];
        *(uint4*)(Bt + ((size_t)(g * NH + n0 + nn)) * KTOT + koff + k0 + c * 8) = pk.q;
    }
}

// ---------------------------------------------------------------------------
// Kernel 2: fused GEMM (z = Abuf @ Bt^T + b) + LSTM gate epilogue.
// R7: 32x32x16 MFMA. 128 threads = 2 waves; wave wv owns 64m x 32n x 4g.
// Block tile 128m x 32n x 4g, LDS 32 KB, grid 32x32 = 1024 blocks = 4/CU.
// XOR-swizzled LDS rows (64 elem = 128 B): LDS chunk c holds global chunk
// c ^ (row&7); conflict-free (8 lanes per 16B granule group).
// Per wave-iter: 24 ds_read_b128, 32 MFMA (b-frag feeds 2 MFMAs, R4 pattern).
// acc = 2mt x 4g x f32x16 = 128 AGPR.
// ---------------------------------------------------------------------------
__global__ __launch_bounds__(128, 2) void lstm_gemm_kernel(
    const u16* __restrict__ Abuf, const float* __restrict__ c0,
    const u16* __restrict__ Bt,
    const float* __restrict__ bfv, const float* __restrict__ biv,
    const float* __restrict__ bov, const float* __restrict__ bcv,
    float* __restrict__ out)
{
    __shared__ u16 As[BM * BK];      // [m][k] row-major (swizzled), 16 KB
    __shared__ u16 Bs[4 * BN * BK];  // [(g*32+n)][k] row-major (swizzled), 16 KB

    const int tid  = threadIdx.x;
    const int wv   = tid >> 6;       // 0..1
    const int lane = tid & 63;
    const int m0 = blockIdx.x * BM;
    const int n0 = blockIdx.y * BN;

    const int lr  = lane >> 3;               // 0..7 (row within 8-row group)
    const int lcs = ((lane & 7) ^ lr) * 8;   // swizzled global k-chunk offset

    f32x16 acc[2][4];                // [mtile][gate]
#pragma unroll
    for (int mt = 0; mt < 2; mt++)
#pragma unroll
        for (int g = 0; g < 4; g++)
#pragma unroll
            for (int e = 0; e < 16; e++)
                acc[mt][g][e] = 0.f;

    const int an   = lane & 31;      // m for A-frag / n for B-frag
    const int an7  = lane & 7;
    const int half = lane >> 5;      // k-half selector (k = half*8 + j)

    for (int k0 = 0; k0 < KTOT; k0 += BK) {
        // Stage A: 128 rows x 64k bf16 = 16 KB, 8 issues/wave (1 KB each)
#pragma unroll
        for (int j = 0; j < 8; j++) {
            int r = (wv * 8 + j) * 8 + lr;
            gload_lds16(Abuf + (size_t)(m0 + r) * KTOT + k0 + lcs,
                        (void*)(As + (wv * 8 + j) * 512));
        }
        // Stage B: 4 gates x 32n x 64k = 16 KB, 8 issues/wave
#pragma unroll
        for (int j = 0; j < 8; j++) {
            int rowIdx = (wv * 8 + j) * 8 + lr;           // g*32+n, 0..127
            int grow = (rowIdx >> 5) * NH + n0 + (rowIdx & 31);
            gload_lds16(Bt + (size_t)grow * KTOT + k0 + lcs,
                        (void*)(Bs + (wv * 8 + j) * 512));
        }
        __syncthreads();
#pragma unroll
        for (int ks = 0; ks < 4; ks++) {                  // K16 steps
            const int sw = (((ks * 2 + half) ^ an7) << 3);   // un-swizzle
            short8 a0 = *(const short8*)(As + (wv * 64 +      an) * BK + sw);
            short8 a1 = *(const short8*)(As + (wv * 64 + 32 + an) * BK + sw);
#pragma unroll
            for (int g = 0; g < 4; g++) {
                short8 b = *(const short8*)(Bs + (g * 32 + an) * BK + sw);
                acc[0][g] = __builtin_amdgcn_mfma_f32_32x32x16_bf16(a0, b, acc[0][g], 0, 0, 0);
                acc[1][g] = __builtin_amdgcn_mfma_f32_32x32x16_bf16(a1, b, acc[1][g], 0, 0, 0);
            }
        }
        __syncthreads();
    }

    // Epilogue. 32x32 C/D layout: col=lane&31, row=(reg&3)+8*(reg>>2)+4*half.
    const int col = n0 + an;
    float bias0 = bfv[col], bias1 = biv[col], bias2 = bov[col], bias3 = bcv[col];

    const size_t HN = (size_t)BATCH * NH;   // 4M elements per output tensor
#pragma unroll
    for (int mt = 0; mt < 2; mt++) {
#pragma unroll
        for (int reg = 0; reg < 16; reg++) {
            const int row = m0 + wv * 64 + mt * 32 +
                            (reg & 3) + 8 * (reg >> 2) + 4 * half;
            const size_t off = (size_t)row * NH + col;
            float zf = acc[mt][0][reg] + bias0;
            float zi = acc[mt][1][reg] + bias1;
            float zo = acc[mt][2][reg] + bias2;
            float zc = acc[mt][3][reg] + bias3;
            float fg = hsig(zf), ig = hsig(zi), og = hsig(zo);
            float ct = fast_tanh(zc);
            float cn = fg * c0[off] + ig * ct;
            float hn = og * fast_tanh(cn);
            out[off]            = hn;   // h
            out[HN + off]       = cn;   // c
            out[2 * HN + off]   = hn;   // h (duplicate output)
        }
    }
}

extern "C" void kernel_launch(void* const* d_in, const int* in_sizes, int n_in,
                              void* d_out, int out_size, void* d_ws, size_t ws_size,
                              hipStream_t stream) {
    const float* x  = (const float*)d_in[0];
    const float* c0 = (const float*)d_in[1];
    const float* h0 = (const float*)d_in[2];
    const float* Wf = (const float*)d_in[3];
    const float* Wi = (const float*)d_in[4];
    const float* Wo = (const float*)d_in[5];
    const float* Wc = (const float*)d_in[6];
    const float* Uf = (const float*)d_in[7];
    const float* Ui = (const float*)d_in[8];
    const float* Uo = (const float*)d_in[9];
    const float* Uc = (const float*)d_in[10];
    const float* bf = (const float*)d_in[11];
    const float* bi = (const float*)d_in[12];
    const float* bo = (const float*)d_in[13];
    const float* bc = (const float*)d_in[14];

    u16* Bt   = (u16*)d_ws;                          // 4096 x 2048 bf16 = 16 MB
    u16* Abuf = (u16*)d_ws + (size_t)4 * NH * KTOT;  // 4096 x 2048 bf16 = 16 MB

    acast_kernel<<<(BATCH * KTOT / 8) / 256, 256, 0, stream>>>(x, h0, Abuf);

    dim3 tg(1024 / 64, 1024 / 64, 8);
    wtrans_kernel<<<tg, 256, 0, stream>>>(Wf, Wi, Wo, Wc, Uf, Ui, Uo, Uc, Bt);

    dim3 gg(BATCH / BM, NH / BN);   // 32 x 32 = 1024 blocks, 4/CU
    lstm_gemm_kernel<<<gg, 128, 0, stream>>>(Abuf, c0, Bt, bf, bi, bo, bc,
                                             (float*)d_out);
}

// Round 8
// 218.057 us; speedup vs baseline: 1.0446x; 1.0446x over previous
//
#include <hip/hip_runtime.h>
#include <hip/hip_bf16.h>
#include <stdint.h>

typedef unsigned short u16;
typedef __attribute__((ext_vector_type(8))) short short8;
typedef __attribute__((ext_vector_type(4))) float f32x4;

#define BATCH 4096
#define DIN   1024
#define NH    1024
#define KTOT  2048
#define BM    128
#define BN    32
#define BK    64

__device__ __forceinline__ void gload_lds16(const void* gp, void* lp) {
    __builtin_amdgcn_global_load_lds(
        (const __attribute__((address_space(1))) uint32_t*)gp,
        (__attribute__((address_space(3))) uint32_t*)lp, 16, 0, 0);
}

__device__ __forceinline__ u16 f2bf(float f) {   // round-to-nearest-even
    uint32_t t; __builtin_memcpy(&t, &f, 4);
    uint32_t r = (t + 0x7FFFu + ((t >> 16) & 1u)) >> 16;
    return (u16)r;
}
__device__ __forceinline__ float hsig(float z) {
    return fminf(fmaxf(fmaf(z, 0.2f, 0.5f), 0.0f), 1.0f);
}
__device__ __forceinline__ float fast_tanh(float x) {
    x = fminf(fmaxf(x, -12.0f), 12.0f);
    float e = __expf(2.0f * x);
    return (e - 1.0f) / (e + 1.0f);
}

// ---------------------------------------------------------------------------
// Fused prep kernel (one launch):
//   blocks [0, 2048):      weight cast+transpose+concat -> Bt[(g*NH+n)][KTOT]
//   blocks [2048, 18432):  activation cast+concat       -> Abuf[m][KTOT]
// ---------------------------------------------------------------------------
#define WT_BLOCKS 2048
__global__ __launch_bounds__(256) void prep_kernel(
    const float* __restrict__ x, const float* __restrict__ h0,
    const float* __restrict__ Wf, const float* __restrict__ Wi,
    const float* __restrict__ Wo, const float* __restrict__ Wc,
    const float* __restrict__ Uf, const float* __restrict__ Ui,
    const float* __restrict__ Uo, const float* __restrict__ Uc,
    u16* __restrict__ Bt, u16* __restrict__ Abuf)
{
    __shared__ u16 tile[64][65];   // 65: store-phase reads spread all banks
    const int bid = blockIdx.x;
    const int tid = threadIdx.x;

    if (bid < WT_BLOCKS) {
        // ---- weight transpose tile: mz = bid>>8, k0 = ((bid>>4)&15)*64, n0 = (bid&15)*64
        const int mz = bid >> 8;       // 0..7: Wf,Wi,Wo,Wc,Uf,Ui,Uo,Uc
        const float* srcs[8] = {Wf, Wi, Wo, Wc, Uf, Ui, Uo, Uc};
        const float* src = srcs[mz];
        const int g    = mz & 3;
        const int koff = (mz >> 2) << 10;
        const int k0 = ((bid >> 4) & 15) * 64;
        const int n0 = (bid & 15) * 64;

#pragma unroll
        for (int i = 0; i < 4; i++) {
            int idx = i * 256 + tid;
            int kk = idx >> 4, c = idx & 15;
            float4 v = *(const float4*)(src + (size_t)(k0 + kk) * NH + n0 + c * 4);
            u16* dst = &tile[kk][c * 4];
            dst[0] = f2bf(v.x); dst[1] = f2bf(v.y);
            dst[2] = f2bf(v.z); dst[3] = f2bf(v.w);
        }
        __syncthreads();
#pragma unroll
        for (int i = 0; i < 2; i++) {
            int idx = i * 256 + tid;
            int nn = idx >> 3, c = idx & 7;
            union { u16 v[8]; uint4 q; } pk;
#pragma unroll
            for (int j = 0; j < 8; j++) pk.v[j] = tile[c * 8 + j][nn];
            *(uint4*)(Bt + ((size_t)(g * NH + n0 + nn)) * KTOT + koff + k0 + c * 8) = pk.q;
        }
    } else {
        // ---- activation cast: 16384 blocks x 256 threads x 8 elems
        const int c  = (bid - WT_BLOCKS) * 256 + tid;    // chunk id
        const int m  = c >> 8;                           // 256 chunks/row
        const int kc = (c & 255) * 8;
        const float* src = (kc < DIN) ? (x + (size_t)m * DIN + kc)
                                      : (h0 + (size_t)m * DIN + (kc - DIN));
        float4 v0 = *(const float4*)(src);
        float4 v1 = *(const float4*)(src + 4);
        union { u16 v[8]; uint4 q; } pk;
        pk.v[0] = f2bf(v0.x); pk.v[1] = f2bf(v0.y);
        pk.v[2] = f2bf(v0.z); pk.v[3] = f2bf(v0.w);
        pk.v[4] = f2bf(v1.x); pk.v[5] = f2bf(v1.y);
        pk.v[6] = f2bf(v1.z); pk.v[7] = f2bf(v1.w);
        *(uint4*)(Abuf + (size_t)m * KTOT + kc) = pk.q;
    }
}

// ---------------------------------------------------------------------------
// Kernel 2: fused GEMM (z = Abuf @ Bt^T + b) + LSTM gate epilogue.
// == R6 structure (session best: 84.4 us GEMM, conflicts 0) ==
// 4 waves split M (32m each), full 32n x 4 gates per wave; BN=32 ->
// grid 32x32 = 1024 blocks = 4 blocks/CU, 16 waves/CU. LDS 32 KB.
// XOR-swizzled LDS rows: chunk c holds global chunk c^(row&7); frag reads
// un-swizzle -> all 8 16B-granule groups active, SQ_LDS_BANK_CONFLICT=0.
// ---------------------------------------------------------------------------
__global__ __launch_bounds__(256, 2) void lstm_gemm_kernel(
    const u16* __restrict__ Abuf, const float* __restrict__ c0,
    const u16* __restrict__ Bt,
    const float* __restrict__ bfv, const float* __restrict__ biv,
    const float* __restrict__ bov, const float* __restrict__ bcv,
    float* __restrict__ out)
{
    __shared__ u16 As[BM * BK];      // [m][k] row-major (swizzled), 16 KB
    __shared__ u16 Bs[4 * BN * BK];  // [(g*32+n)][k] row-major (swizzled), 16 KB

    const int tid  = threadIdx.x;
    const int wv   = tid >> 6;
    const int lane = tid & 63;
    const int m0 = blockIdx.x * BM;
    const int n0 = blockIdx.y * BN;

    const int lr  = lane >> 3;               // 0..7 (row within 8-row group)
    const int lcs = ((lane & 7) ^ lr) * 8;   // swizzled global k-chunk offset

    f32x4 acc[2][4][2];              // [mtile][gate][ntile]
#pragma unroll
    for (int mt = 0; mt < 2; mt++)
#pragma unroll
        for (int g = 0; g < 4; g++)
#pragma unroll
            for (int nt = 0; nt < 2; nt++)
                acc[mt][g][nt] = (f32x4){0.f, 0.f, 0.f, 0.f};

    const int am   = lane & 15;
    const int am7  = am & 7;
    const int quad = lane >> 4;

    for (int k0 = 0; k0 < KTOT; k0 += BK) {
        // Stage A: 128x64 bf16 = 16 KB, 4 issues/wave (1 KB each)
#pragma unroll
        for (int j = 0; j < 4; j++) {
            int r = (wv * 4 + j) * 8 + lr;
            gload_lds16(Abuf + (size_t)(m0 + r) * KTOT + k0 + lcs,
                        (void*)(As + (wv * 4 + j) * 512));
        }
        // Stage B: 4 gates x 32n x 64k = 16 KB, 4 issues/wave
#pragma unroll
        for (int j = 0; j < 4; j++) {
            int rowIdx = (wv * 4 + j) * 8 + lr;           // g*32+n, 0..127
            int grow = (rowIdx >> 5) * NH + n0 + (rowIdx & 31);
            gload_lds16(Bt + (size_t)grow * KTOT + k0 + lcs,
                        (void*)(Bs + (wv * 4 + j) * 512));
        }
        __syncthreads();
#pragma unroll
        for (int ks = 0; ks < 2; ks++) {
            const int sw = (((ks * 4 + quad) ^ am7) << 3);   // un-swizzle
            short8 a0 = *(const short8*)(As + (wv * 32 +      am) * BK + sw);
            short8 a1 = *(const short8*)(As + (wv * 32 + 16 + am) * BK + sw);
#pragma unroll
            for (int g = 0; g < 4; g++) {
#pragma unroll
                for (int nt = 0; nt < 2; nt++) {
                    short8 b = *(const short8*)(Bs + (g * 32 + nt * 16 + am) * BK + sw);
                    acc[0][g][nt] = __builtin_amdgcn_mfma_f32_16x16x32_bf16(a0, b, acc[0][g][nt], 0, 0, 0);
                    acc[1][g][nt] = __builtin_amdgcn_mfma_f32_16x16x32_bf16(a1, b, acc[1][g][nt], 0, 0, 0);
                }
            }
        }
        __syncthreads();
    }

    // Epilogue: z -> gates -> c,h. C/D layout: col=lane&15, row=quad*4+reg.
    float bias[4][2];                 // [gate][ntile]
    const float* bptr[4] = {bfv, biv, bov, bcv};
#pragma unroll
    for (int g = 0; g < 4; g++)
#pragma unroll
        for (int nt = 0; nt < 2; nt++)
            bias[g][nt] = bptr[g][n0 + nt * 16 + am];

    const size_t HN = (size_t)BATCH * NH;   // 4M elements per output tensor
#pragma unroll
    for (int mt = 0; mt < 2; mt++) {
#pragma unroll
        for (int r = 0; r < 4; r++) {
            const int row = m0 + wv * 32 + mt * 16 + quad * 4 + r;
#pragma unroll
            for (int nt = 0; nt < 2; nt++) {
                const int col = n0 + nt * 16 + am;
                const size_t off = (size_t)row * NH + col;
                float zf = acc[mt][0][nt][r] + bias[0][nt];
                float zi = acc[mt][1][nt][r] + bias[1][nt];
                float zo = acc[mt][2][nt][r] + bias[2][nt];
                float zc = acc[mt][3][nt][r] + bias[3][nt];
                float fg = hsig(zf), ig = hsig(zi), og = hsig(zo);
                float ct = fast_tanh(zc);
                float cn = fg * c0[off] + ig * ct;
                float hn = og * fast_tanh(cn);
                out[off]            = hn;   // h
                out[HN + off]       = cn;   // c
                out[2 * HN + off]   = hn;   // h (duplicate output)
            }
        }
    }
}

extern "C" void kernel_launch(void* const* d_in, const int* in_sizes, int n_in,
                              void* d_out, int out_size, void* d_ws, size_t ws_size,
                              hipStream_t stream) {
    const float* x  = (const float*)d_in[0];
    const float* c0 = (const float*)d_in[1];
    const float* h0 = (const float*)d_in[2];
    const float* Wf = (const float*)d_in[3];
    const float* Wi = (const float*)d_in[4];
    const float* Wo = (const float*)d_in[5];
    const float* Wc = (const float*)d_in[6];
    const float* Uf = (const float*)d_in[7];
    const float* Ui = (const float*)d_in[8];
    const float* Uo = (const float*)d_in[9];
    const float* Uc = (const float*)d_in[10];
    const float* bf = (const float*)d_in[11];
    const float* bi = (const float*)d_in[12];
    const float* bo = (const float*)d_in[13];
    const float* bc = (const float*)d_in[14];

    u16* Bt   = (u16*)d_ws;                          // 4096 x 2048 bf16 = 16 MB
    u16* Abuf = (u16*)d_ws + (size_t)4 * NH * KTOT;  // 4096 x 2048 bf16 = 16 MB

    // One fused prep launch: 2048 transpose blocks + 16384 cast blocks
    prep_kernel<<<WT_BLOCKS + (BATCH * KTOT / 8) / 256, 256, 0, stream>>>(
        x, h0, Wf, Wi, Wo, Wc, Uf, Ui, Uo, Uc, Bt, Abuf);

    dim3 gg(BATCH / BM, NH / BN);   // 32 x 32 = 1024 blocks, 4/CU
    lstm_gemm_kernel<<<gg, 256, 0, stream>>>(Abuf, c0, Bt, bf, bi, bo, bc,
                                             (float*)d_out);
}

// Round 9
// 216.265 us; speedup vs baseline: 1.0533x; 1.0083x over previous
//
#include <hip/hip_runtime.h>
#include <hip/hip_bf16.h>
#include <stdint.h>

typedef unsigned short u16;
typedef __attribute__((ext_vector_type(8))) short short8;
typedef __attribute__((ext_vector_type(4))) float f32x4;

#define BATCH 4096
#define DIN   1024
#define NH    1024
#define KTOT  2048
#define BM    128
#define BN    32
#define BK    64

__device__ __forceinline__ void gload_lds16(const void* gp, void* lp) {
    __builtin_amdgcn_global_load_lds(
        (const __attribute__((address_space(1))) uint32_t*)gp,
        (__attribute__((address_space(3))) uint32_t*)lp, 16, 0, 0);
}

__device__ __forceinline__ u16 f2bf(float f) {   // round-to-nearest-even
    uint32_t t; __builtin_memcpy(&t, &f, 4);
    uint32_t r = (t + 0x7FFFu + ((t >> 16) & 1u)) >> 16;
    return (u16)r;
}
__device__ __forceinline__ float hsig(float z) {
    return fminf(fmaxf(fmaf(z, 0.2f, 0.5f), 0.0f), 1.0f);
}
__device__ __forceinline__ float fast_tanh(float x) {
    x = fminf(fmaxf(x, -12.0f), 12.0f);
    float e = __expf(2.0f * x);
    return (e - 1.0f) / (e + 1.0f);
}

// ---------------------------------------------------------------------------
// Fused prep kernel (one launch):
//   blocks [0, 2048):      weight cast+transpose+concat -> Bt[(g*NH+n)][KTOT]
//   blocks [2048, 18432):  activation cast+concat       -> Abuf[m][KTOT]
// ---------------------------------------------------------------------------
#define WT_BLOCKS 2048
__global__ __launch_bounds__(256) void prep_kernel(
    const float* __restrict__ x, const float* __restrict__ h0,
    const float* __restrict__ Wf, const float* __restrict__ Wi,
    const float* __restrict__ Wo, const float* __restrict__ Wc,
    const float* __restrict__ Uf, const float* __restrict__ Ui,
    const float* __restrict__ Uo, const float* __restrict__ Uc,
    u16* __restrict__ Bt, u16* __restrict__ Abuf)
{
    __shared__ u16 tile[64][65];   // 65: store-phase reads spread all banks
    const int bid = blockIdx.x;
    const int tid = threadIdx.x;

    if (bid < WT_BLOCKS) {
        const int mz = bid >> 8;       // 0..7: Wf,Wi,Wo,Wc,Uf,Ui,Uo,Uc
        const float* srcs[8] = {Wf, Wi, Wo, Wc, Uf, Ui, Uo, Uc};
        const float* src = srcs[mz];
        const int g    = mz & 3;
        const int koff = (mz >> 2) << 10;
        const int k0 = ((bid >> 4) & 15) * 64;
        const int n0 = (bid & 15) * 64;

#pragma unroll
        for (int i = 0; i < 4; i++) {
            int idx = i * 256 + tid;
            int kk = idx >> 4, c = idx & 15;
            float4 v = *(const float4*)(src + (size_t)(k0 + kk) * NH + n0 + c * 4);
            u16* dst = &tile[kk][c * 4];
            dst[0] = f2bf(v.x); dst[1] = f2bf(v.y);
            dst[2] = f2bf(v.z); dst[3] = f2bf(v.w);
        }
        __syncthreads();
#pragma unroll
        for (int i = 0; i < 2; i++) {
            int idx = i * 256 + tid;
            int nn = idx >> 3, c = idx & 7;
            union { u16 v[8]; uint4 q; } pk;
#pragma unroll
            for (int j = 0; j < 8; j++) pk.v[j] = tile[c * 8 + j][nn];
            *(uint4*)(Bt + ((size_t)(g * NH + n0 + nn)) * KTOT + koff + k0 + c * 8) = pk.q;
        }
    } else {
        const int c  = (bid - WT_BLOCKS) * 256 + tid;    // chunk id
        const int m  = c >> 8;                           // 256 chunks/row
        const int kc = (c & 255) * 8;
        const float* src = (kc < DIN) ? (x + (size_t)m * DIN + kc)
                                      : (h0 + (size_t)m * DIN + (kc - DIN));
        float4 v0 = *(const float4*)(src);
        float4 v1 = *(const float4*)(src + 4);
        union { u16 v[8]; uint4 q; } pk;
        pk.v[0] = f2bf(v0.x); pk.v[1] = f2bf(v0.y);
        pk.v[2] = f2bf(v0.z); pk.v[3] = f2bf(v0.w);
        pk.v[4] = f2bf(v1.x); pk.v[5] = f2bf(v1.y);
        pk.v[6] = f2bf(v1.z); pk.v[7] = f2bf(v1.w);
        *(uint4*)(Abuf + (size_t)m * KTOT + kc) = pk.q;
    }
}

// ---------------------------------------------------------------------------
// Kernel 2: fused GEMM (z = Abuf @ Bt^T + b) + LSTM gate epilogue.
// R9: same block tile as R6/R8 (128m x 32n x 4g, 32 KB LDS, 1024 blocks =
// 4/CU, 16 waves/CU) but waves arranged 2x2: wave owns 64m x (16n x 4g).
// Outer product Ra=4 x Rb=4 -> 8 ds_read_b128 per 16 MFMA (was 10/16):
// -20% LDS-pipe instructions at IDENTICAL occupancy.
// XOR-swizzled LDS rows (verified conflict-free R4/R6/R8).
// XCD swizzle: blocks on XCD c compute y in {4c..4c+3} -> 2 MB of Bt/L2.
// ---------------------------------------------------------------------------
__global__ __launch_bounds__(256, 2) void lstm_gemm_kernel(
    const u16* __restrict__ Abuf, const float* __restrict__ c0,
    const u16* __restrict__ Bt,
    const float* __restrict__ bfv, const float* __restrict__ biv,
    const float* __restrict__ bov, const float* __restrict__ bcv,
    float* __restrict__ out)
{
    __shared__ u16 As[BM * BK];      // [m][k] row-major (swizzled), 16 KB
    __shared__ u16 Bs[4 * BN * BK];  // [(g*32+n)][k] row-major (swizzled), 16 KB

    const int tid  = threadIdx.x;
    const int wv   = tid >> 6;
    const int lane = tid & 63;

    // XCD-aware remap of 1-D block id -> (bx, by)
    const int b   = blockIdx.x;
    const int xcd = b & 7;
    const int q   = b >> 3;
    const int by  = xcd * 4 + (q >> 5);   // 0..31 (n-strip)
    const int bx  = q & 31;               // 0..31 (m-strip)
    const int m0 = bx * BM;
    const int n0 = by * BN;

    const int wr = (wv >> 1) * 64;   // wave m-offset: 0 or 64
    const int wc = (wv & 1) * 16;    // wave n-offset within each gate: 0 or 16

    const int lr  = lane >> 3;               // 0..7 (row within 8-row group)
    const int lcs = ((lane & 7) ^ lr) * 8;   // swizzled global k-chunk offset

    f32x4 acc[4][4];                 // [mtile][gate]
#pragma unroll
    for (int mt = 0; mt < 4; mt++)
#pragma unroll
        for (int g = 0; g < 4; g++)
            acc[mt][g] = (f32x4){0.f, 0.f, 0.f, 0.f};

    const int am   = lane & 15;
    const int am7  = am & 7;
    const int quad = lane >> 4;

    for (int k0 = 0; k0 < KTOT; k0 += BK) {
        // Stage A: 128x64 bf16 = 16 KB, 4 issues/wave (1 KB each)
#pragma unroll
        for (int j = 0; j < 4; j++) {
            int r = (wv * 4 + j) * 8 + lr;
            gload_lds16(Abuf + (size_t)(m0 + r) * KTOT + k0 + lcs,
                        (void*)(As + (wv * 4 + j) * 512));
        }
        // Stage B: 4 gates x 32n x 64k = 16 KB, 4 issues/wave
#pragma unroll
        for (int j = 0; j < 4; j++) {
            int rowIdx = (wv * 4 + j) * 8 + lr;           // g*32+n, 0..127
            int grow = (rowIdx >> 5) * NH + n0 + (rowIdx & 31);
            gload_lds16(Bt + (size_t)grow * KTOT + k0 + lcs,
                        (void*)(Bs + (wv * 4 + j) * 512));
        }
        __syncthreads();
#pragma unroll
        for (int ks = 0; ks < 2; ks++) {
            const int sw = (((ks * 4 + quad) ^ am7) << 3);   // un-swizzle
            short8 a[4];
#pragma unroll
            for (int mt = 0; mt < 4; mt++)
                a[mt] = *(const short8*)(As + (wr + mt * 16 + am) * BK + sw);
#pragma unroll
            for (int g = 0; g < 4; g++) {
                short8 bfrag = *(const short8*)(Bs + (g * 32 + wc + am) * BK + sw);
#pragma unroll
                for (int mt = 0; mt < 4; mt++)
                    acc[mt][g] = __builtin_amdgcn_mfma_f32_16x16x32_bf16(
                        a[mt], bfrag, acc[mt][g], 0, 0, 0);
            }
        }
        __syncthreads();
    }

    // Epilogue: z -> gates -> c,h. C/D layout: col=lane&15, row=quad*4+reg.
    const int col = n0 + wc + am;
    float bias0 = bfv[col], bias1 = biv[col], bias2 = bov[col], bias3 = bcv[col];

    const size_t HN = (size_t)BATCH * NH;   // 4M elements per output tensor
#pragma unroll
    for (int mt = 0; mt < 4; mt++) {
#pragma unroll
        for (int r = 0; r < 4; r++) {
            const int row = m0 + wr + mt * 16 + quad * 4 + r;
            const size_t off = (size_t)row * NH + col;
            float zf = acc[mt][0][r] + bias0;
            float zi = acc[mt][1][r] + bias1;
            float zo = acc[mt][2][r] + bias2;
            float zc = acc[mt][3][r] + bias3;
            float fg = hsig(zf), ig = hsig(zi), og = hsig(zo);
            float ct = fast_tanh(zc);
            float cn = fg * c0[off] + ig * ct;
            float hn = og * fast_tanh(cn);
            out[off]            = hn;   // h
            out[HN + off]       = cn;   // c
            out[2 * HN + off]   = hn;   // h (duplicate output)
        }
    }
}

extern "C" void kernel_launch(void* const* d_in, const int* in_sizes, int n_in,
                              void* d_out, int out_size, void* d_ws, size_t ws_size,
                              hipStream_t stream) {
    const float* x  = (const float*)d_in[0];
    const float* c0 = (const float*)d_in[1];
    const float* h0 = (const float*)d_in[2];
    const float* Wf = (const float*)d_in[3];
    const float* Wi = (const float*)d_in[4];
    const float* Wo = (const float*)d_in[5];
    const float* Wc = (const float*)d_in[6];
    const float* Uf = (const float*)d_in[7];
    const float* Ui = (const float*)d_in[8];
    const float* Uo = (const float*)d_in[9];
    const float* Uc = (const float*)d_in[10];
    const float* bf = (const float*)d_in[11];
    const float* bi = (const float*)d_in[12];
    const float* bo = (const float*)d_in[13];
    const float* bc = (const float*)d_in[14];

    u16* Bt   = (u16*)d_ws;                          // 4096 x 2048 bf16 = 16 MB
    u16* Abuf = (u16*)d_ws + (size_t)4 * NH * KTOT;  // 4096 x 2048 bf16 = 16 MB

    prep_kernel<<<WT_BLOCKS + (BATCH * KTOT / 8) / 256, 256, 0, stream>>>(
        x, h0, Wf, Wi, Wo, Wc, Uf, Ui, Uo, Uc, Bt, Abuf);

    lstm_gemm_kernel<<<1024, 256, 0, stream>>>(Abuf, c0, Bt, bf, bi, bo, bc,
                                               (float*)d_out);
}

// Round 10
// 213.091 us; speedup vs baseline: 1.0690x; 1.0149x over previous
//
#include <hip/hip_runtime.h>
#include <hip/hip_bf16.h>
#include <stdint.h>

typedef unsigned short u16;
typedef __attribute__((ext_vector_type(8))) short short8;
typedef __attribute__((ext_vector_type(4))) float f32x4;

#define BATCH 4096
#define DIN   1024
#define NH    1024
#define KTOT  2048
#define BM    128
#define BN    32
#define BK    64

__device__ __forceinline__ void gload_lds16(const void* gp, void* lp) {
    __builtin_amdgcn_global_load_lds(
        (const __attribute__((address_space(1))) uint32_t*)gp,
        (__attribute__((address_space(3))) uint32_t*)lp, 16, 0, 0);
}

__device__ __forceinline__ u16 f2bf(float f) {   // round-to-nearest-even
    uint32_t t; __builtin_memcpy(&t, &f, 4);
    uint32_t r = (t + 0x7FFFu + ((t >> 16) & 1u)) >> 16;
    return (u16)r;
}
__device__ __forceinline__ float hsig(float z) {
    return fminf(fmaxf(fmaf(z, 0.2f, 0.5f), 0.0f), 1.0f);
}
__device__ __forceinline__ float fast_tanh(float x) {
    x = fminf(fmaxf(x, -12.0f), 12.0f);
    float e = __expf(2.0f * x);
    return (e - 1.0f) / (e + 1.0f);
}

// ---------------------------------------------------------------------------
// Fused prep kernel (one launch):
//   blocks [0, 2048):      weight cast+transpose+concat -> Bt[(g*NH+n)][KTOT]
//   blocks [2048, 18432):  activation cast+concat       -> Abuf[m][KTOT]
// HBM-bound: ~128 MB total traffic ~= 20 us floor.
// ---------------------------------------------------------------------------
#define WT_BLOCKS 2048
__global__ __launch_bounds__(256) void prep_kernel(
    const float* __restrict__ x, const float* __restrict__ h0,
    const float* __restrict__ Wf, const float* __restrict__ Wi,
    const float* __restrict__ Wo, const float* __restrict__ Wc,
    const float* __restrict__ Uf, const float* __restrict__ Ui,
    const float* __restrict__ Uo, const float* __restrict__ Uc,
    u16* __restrict__ Bt, u16* __restrict__ Abuf)
{
    __shared__ u16 tile[64][65];   // 65: store-phase reads spread all banks
    const int bid = blockIdx.x;
    const int tid = threadIdx.x;

    if (bid < WT_BLOCKS) {
        const int mz = bid >> 8;       // 0..7: Wf,Wi,Wo,Wc,Uf,Ui,Uo,Uc
        const float* srcs[8] = {Wf, Wi, Wo, Wc, Uf, Ui, Uo, Uc};
        const float* src = srcs[mz];
        const int g    = mz & 3;
        const int koff = (mz >> 2) << 10;
        const int k0 = ((bid >> 4) & 15) * 64;
        const int n0 = (bid & 15) * 64;

#pragma unroll
        for (int i = 0; i < 4; i++) {
            int idx = i * 256 + tid;
            int kk = idx >> 4, c = idx & 15;
            float4 v = *(const float4*)(src + (size_t)(k0 + kk) * NH + n0 + c * 4);
            u16* dst = &tile[kk][c * 4];
            dst[0] = f2bf(v.x); dst[1] = f2bf(v.y);
            dst[2] = f2bf(v.z); dst[3] = f2bf(v.w);
        }
        __syncthreads();
#pragma unroll
        for (int i = 0; i < 2; i++) {
            int idx = i * 256 + tid;
            int nn = idx >> 3, c = idx & 7;
            union { u16 v[8]; uint4 q; } pk;
#pragma unroll
            for (int j = 0; j < 8; j++) pk.v[j] = tile[c * 8 + j][nn];
            *(uint4*)(Bt + ((size_t)(g * NH + n0 + nn)) * KTOT + koff + k0 + c * 8) = pk.q;
        }
    } else {
        const int c  = (bid - WT_BLOCKS) * 256 + tid;    // chunk id
        const int m  = c >> 8;                           // 256 chunks/row
        const int kc = (c & 255) * 8;
        const float* src = (kc < DIN) ? (x + (size_t)m * DIN + kc)
                                      : (h0 + (size_t)m * DIN + (kc - DIN));
        float4 v0 = *(const float4*)(src);
        float4 v1 = *(const float4*)(src + 4);
        union { u16 v[8]; uint4 q; } pk;
        pk.v[0] = f2bf(v0.x); pk.v[1] = f2bf(v0.y);
        pk.v[2] = f2bf(v0.z); pk.v[3] = f2bf(v0.w);
        pk.v[4] = f2bf(v1.x); pk.v[5] = f2bf(v1.y);
        pk.v[6] = f2bf(v1.z); pk.v[7] = f2bf(v1.w);
        *(uint4*)(Abuf + (size_t)m * KTOT + kc) = pk.q;
    }
}

// ---------------------------------------------------------------------------
// Kernel 2: fused GEMM (z = Abuf @ Bt^T + b) + LSTM gate epilogue.
// R10 = R9 wave tiling (2x2: wave owns 64m x 16n x 4g, Ra=4 x Rb=4 outer
// product, 8 ds_read_b128 per 16 MFMA) with the XCD remap REVERTED (R9's
// remap doubled FETCH_SIZE 86->161 MB; plain 2-D grid measured 86 MB in R8).
// Block tile 128m x 32n x 4g, 32 KB LDS, grid 32x32 = 1024 blocks = 4/CU,
// 16 waves/CU. XOR-swizzled LDS rows (SQ_LDS_BANK_CONFLICT=0, R4/R6/R8/R9).
// Structure note: this is the m97-class 2-barrier K-loop; measured plateau
// ~850 TF (R4-R9: 80-95 us across occupancy/LDS/MFMA-shape variations).
// ---------------------------------------------------------------------------
__global__ __launch_bounds__(256, 2) void lstm_gemm_kernel(
    const u16* __restrict__ Abuf, const float* __restrict__ c0,
    const u16* __restrict__ Bt,
    const float* __restrict__ bfv, const float* __restrict__ biv,
    const float* __restrict__ bov, const float* __restrict__ bcv,
    float* __restrict__ out)
{
    __shared__ u16 As[BM * BK];      // [m][k] row-major (swizzled), 16 KB
    __shared__ u16 Bs[4 * BN * BK];  // [(g*32+n)][k] row-major (swizzled), 16 KB

    const int tid  = threadIdx.x;
    const int wv   = tid >> 6;
    const int lane = tid & 63;
    const int m0 = blockIdx.x * BM;
    const int n0 = blockIdx.y * BN;

    const int wr = (wv >> 1) * 64;   // wave m-offset: 0 or 64
    const int wc = (wv & 1) * 16;    // wave n-offset within each gate: 0 or 16

    const int lr  = lane >> 3;               // 0..7 (row within 8-row group)
    const int lcs = ((lane & 7) ^ lr) * 8;   // swizzled global k-chunk offset

    f32x4 acc[4][4];                 // [mtile][gate]
#pragma unroll
    for (int mt = 0; mt < 4; mt++)
#pragma unroll
        for (int g = 0; g < 4; g++)
            acc[mt][g] = (f32x4){0.f, 0.f, 0.f, 0.f};

    const int am   = lane & 15;
    const int am7  = am & 7;
    const int quad = lane >> 4;

    for (int k0 = 0; k0 < KTOT; k0 += BK) {
        // Stage A: 128x64 bf16 = 16 KB, 4 issues/wave (1 KB each)
#pragma unroll
        for (int j = 0; j < 4; j++) {
            int r = (wv * 4 + j) * 8 + lr;
            gload_lds16(Abuf + (size_t)(m0 + r) * KTOT + k0 + lcs,
                        (void*)(As + (wv * 4 + j) * 512));
        }
        // Stage B: 4 gates x 32n x 64k = 16 KB, 4 issues/wave
#pragma unroll
        for (int j = 0; j < 4; j++) {
            int rowIdx = (wv * 4 + j) * 8 + lr;           // g*32+n, 0..127
            int grow = (rowIdx >> 5) * NH + n0 + (rowIdx & 31);
            gload_lds16(Bt + (size_t)grow * KTOT + k0 + lcs,
                        (void*)(Bs + (wv * 4 + j) * 512));
        }
        __syncthreads();
#pragma unroll
        for (int ks = 0; ks < 2; ks++) {
            const int sw = (((ks * 4 + quad) ^ am7) << 3);   // un-swizzle
            short8 a[4];
#pragma unroll
            for (int mt = 0; mt < 4; mt++)
                a[mt] = *(const short8*)(As + (wr + mt * 16 + am) * BK + sw);
#pragma unroll
            for (int g = 0; g < 4; g++) {
                short8 bfrag = *(const short8*)(Bs + (g * 32 + wc + am) * BK + sw);
#pragma unroll
                for (int mt = 0; mt < 4; mt++)
                    acc[mt][g] = __builtin_amdgcn_mfma_f32_16x16x32_bf16(
                        a[mt], bfrag, acc[mt][g], 0, 0, 0);
            }
        }
        __syncthreads();
    }

    // Epilogue: z -> gates -> c,h. C/D layout: col=lane&15, row=quad*4+reg.
    const int col = n0 + wc + am;
    float bias0 = bfv[col], bias1 = biv[col], bias2 = bov[col], bias3 = bcv[col];

    const size_t HN = (size_t)BATCH * NH;   // 4M elements per output tensor
#pragma unroll
    for (int mt = 0; mt < 4; mt++) {
#pragma unroll
        for (int r = 0; r < 4; r++) {
            const int row = m0 + wr + mt * 16 + quad * 4 + r;
            const size_t off = (size_t)row * NH + col;
            float zf = acc[mt][0][r] + bias0;
            float zi = acc[mt][1][r] + bias1;
            float zo = acc[mt][2][r] + bias2;
            float zc = acc[mt][3][r] + bias3;
            float fg = hsig(zf), ig = hsig(zi), og = hsig(zo);
            float ct = fast_tanh(zc);
            float cn = fg * c0[off] + ig * ct;
            float hn = og * fast_tanh(cn);
            out[off]            = hn;   // h
            out[HN + off]       = cn;   // c
            out[2 * HN + off]   = hn;   // h (duplicate output)
        }
    }
}

extern "C" void kernel_launch(void* const* d_in, const int* in_sizes, int n_in,
                              void* d_out, int out_size, void* d_ws, size_t ws_size,
                              hipStream_t stream) {
    const float* x  = (const float*)d_in[0];
    const float* c0 = (const float*)d_in[1];
    const float* h0 = (const float*)d_in[2];
    const float* Wf = (const float*)d_in[3];
    const float* Wi = (const float*)d_in[4];
    const float* Wo = (const float*)d_in[5];
    const float* Wc = (const float*)d_in[6];
    const float* Uf = (const float*)d_in[7];
    const float* Ui = (const float*)d_in[8];
    const float* Uo = (const float*)d_in[9];
    const float* Uc = (const float*)d_in[10];
    const float* bf = (const float*)d_in[11];
    const float* bi = (const float*)d_in[12];
    const float* bo = (const float*)d_in[13];
    const float* bc = (const float*)d_in[14];

    u16* Bt   = (u16*)d_ws;                          // 4096 x 2048 bf16 = 16 MB
    u16* Abuf = (u16*)d_ws + (size_t)4 * NH * KTOT;  // 4096 x 2048 bf16 = 16 MB

    prep_kernel<<<WT_BLOCKS + (BATCH * KTOT / 8) / 256, 256, 0, stream>>>(
        x, h0, Wf, Wi, Wo, Wc, Uf, Ui, Uo, Uc, Bt, Abuf);

    dim3 gg(BATCH / BM, NH / BN);   // 32 x 32 = 1024 blocks, 4/CU
    lstm_gemm_kernel<<<gg, 256, 0, stream>>>(Abuf, c0, Bt, bf, bi, bo, bc,
                                             (float*)d_out);
}